// Round 8
// baseline (236.005 us; speedup 1.0000x reference)
//
#include <hip/hip_runtime.h>
#include <hip/hip_bf16.h>
#include <stdint.h>

typedef unsigned short ushort_t;
typedef __attribute__((ext_vector_type(8))) short short8;
typedef __attribute__((ext_vector_type(4))) short short4v;
typedef __attribute__((ext_vector_type(4))) unsigned short ushort4v;
typedef __attribute__((ext_vector_type(4))) float f32x4;

#define L_SEQ   2048
#define BATCH   8
#define M_ROWS  16384          // BATCH*L_SEQ
#define EPSV    1e-5f
#define GEMM_NB 576            // 64 m-tiles x 9 n-tiles
#define DTG_NB  64             // 64 blocks x 256 rows
#define ZL_NB   256            // 256 blocks x 8 cols

__device__ __forceinline__ float bf2f(ushort_t u){
  union { uint32_t i; float f; } v; v.i = ((uint32_t)u) << 16; return v.f;
}
__device__ __forceinline__ ushort_t f2bf(float f){
  union { float f; uint32_t i; } v; v.f = f;
  uint32_t r = v.i + 0x7fffu + ((v.i >> 16) & 1u);
  return (ushort_t)(r >> 16);
}

// ---------------- fused prep: cvt + w1t + wdt + 4 transposes ----------------
__global__ __launch_bounds__(256)
void k_prep(const float* __restrict__ x, const float* __restrict__ w_proj,
            const float* __restrict__ w_in, const float* __restrict__ w_out,
            const float* __restrict__ w_head,
            ushort_t* __restrict__ xb, ushort_t* __restrict__ w1t,
            ushort_t* __restrict__ w2t, ushort_t* __restrict__ wdt,
            float* __restrict__ wzT, float* __restrict__ wot, float* __restrict__ wht){
  __shared__ float tile[64][65];
  int bx = blockIdx.x, tid = threadIdx.x;
  if (bx < 4096){                          // x -> bf16
    int i = bx * 256 + tid;
    xb[i] = f2bf(x[i]);
    return;
  }
  bx -= 4096;
  if (bx < 256){                           // w1t[j*64+k] = w_proj[k*1024+j]
    int i = bx * 256 + tid; int k = i >> 10, j = i & 1023;
    w1t[j * 64 + k] = f2bf(w_proj[i]);
    return;
  }
  bx -= 256;
  if (bx < 128){                           // dt weights hi/lo split
    int i = bx * 256 + tid; int n = i >> 10, k = i & 1023;
    float w = w_in[(size_t)k * 4384 + 4352 + n];
    ushort_t hi = f2bf(w);
    wdt[n * 2048 + k] = hi;
    wdt[n * 2048 + 1024 + k] = f2bf(w - bf2f(hi));
    return;
  }
  bx -= 128;
  const float* src; float* dstf = nullptr; ushort_t* dstb = nullptr;
  int R, C, colOff, j0, k0;
  if (bx < 576){       src = w_in;   dstb = w2t; R = 1024; C = 4384; colOff = 2048; j0 = (bx % 36) * 64; k0 = (bx / 36) * 64; }
  else if ((bx -= 576) < 512){ src = w_in;  dstf = wzT; R = 1024; C = 4384; colOff = 0; j0 = (bx % 32) * 64; k0 = (bx / 32) * 64; }
  else if ((bx -= 512) < 512){ src = w_out; dstf = wot; R = 2048; C = 1024; colOff = 0; j0 = (bx % 16) * 64; k0 = (bx / 16) * 64; }
  else { bx -= 512;    src = w_head; dstf = wht; R = 1024; C = 64;   colOff = 0; j0 = 0;             k0 = bx * 64; }
  int tx = tid & 63, ty = tid >> 6;
  #pragma unroll
  for (int i = 0; i < 16; ++i){
    int kk = ty * 16 + i;
    tile[kk][tx] = src[(size_t)(k0 + kk) * C + colOff + j0 + tx];
  }
  __syncthreads();
  #pragma unroll
  for (int i = 0; i < 16; ++i){
    int jj = ty * 16 + i;
    if (dstb) dstb[(size_t)(j0 + jj) * R + k0 + tx] = f2bf(tile[tx][jj]);
    else      dstf[(size_t)(j0 + jj) * R + k0 + tx] = tile[tx][jj];
  }
}

// ---------------- async global->LDS ----------------
__device__ __forceinline__ void gload16(const void* g, void* l){
  __builtin_amdgcn_global_load_lds((const __attribute__((address_space(1))) void*)g,
                                   (__attribute__((address_space(3))) void*)l, 16, 0, 0);
}
__device__ __forceinline__ void BAR(){
  asm volatile("" ::: "memory");
  __builtin_amdgcn_s_barrier();
  asm volatile("" ::: "memory");
}

// ---------------- fused: 256x256 8-phase GEMM2 + dtg + zlast ----------------
// bid [0,576): gemm C = A*Bt^T ; [576,640): dt GEMM ; [640,896): z_last
__global__ __launch_bounds__(512, 1)
void k_fused256(const ushort_t* __restrict__ A, const ushort_t* __restrict__ Bt,
                ushort_t* __restrict__ C, const ushort_t* __restrict__ wdt,
                float* __restrict__ dtr, const float* __restrict__ wzT,
                float* __restrict__ z_last, int N, int nbx){
  __shared__ ushort_t lds[65536];
  const int bid = blockIdx.x;
  const int tid = threadIdx.x;
  const int lane = tid & 63;
  const int wave = tid >> 6;
  const int l15 = lane & 15, l4 = lane >> 4;

  if (bid >= GEMM_NB + DTG_NB){
    // ---------------- z_last: 8 waves, wave per column ----------------
    int col = (bid - GEMM_NB - DTG_NB) * 8 + wave;
    float acc[8] = {0.f, 0.f, 0.f, 0.f, 0.f, 0.f, 0.f, 0.f};
    const float* wp = wzT + (size_t)col * 1024;
    #pragma unroll 4
    for (int i = 0; i < 16; ++i){
      int k = i * 64 + lane;
      float w = wp[k];
      #pragma unroll
      for (int b = 0; b < 8; ++b)
        acc[b] += bf2f(A[((size_t)b * 2048 + 2047) * 1024 + k]) * w;
    }
    #pragma unroll
    for (int b = 0; b < 8; ++b){
      float v = acc[b];
      for (int s = 32; s; s >>= 1) v += __shfl_down(v, s, 64);
      if (lane == 0) z_last[b * 2048 + col] = v;
    }
    return;
  }

  if (bid >= GEMM_NB){
    // ---------------- dt GEMM: 256 rows/block, 8 waves ----------------
    const int m0 = (bid - GEMM_NB) * 256;
    ushort_t* tA  = lds;            // 256*32
    ushort_t* tBh = lds + 8192;     // 32*32
    ushort_t* tBl = lds + 9216;     // 32*32
    const int srow  = lane >> 2;
    const int skoff = (lane & 3) * 8;
    f32x4 acc[2][2];
    #pragma unroll
    for (int m = 0; m < 2; ++m)
      #pragma unroll
      for (int n = 0; n < 2; ++n)
        #pragma unroll
        for (int r = 0; r < 4; ++r) acc[m][n][r] = 0.f;
    for (int k0 = 0; k0 < 1024; k0 += 32){
      #pragma unroll
      for (int r = 0; r < 2; ++r){
        int chunk = r * 8 + wave;         // 0..15
        int rr = chunk * 16 + srow;       // 0..255
        gload16(A + (size_t)(m0 + rr) * 1024 + k0 + skoff, &tA[chunk * 512]);
      }
      if (wave < 2){
        int rr = wave * 16 + srow;
        gload16(Bt + (size_t)rr * 2048 + k0 + skoff, &tBh[wave * 512]);
      } else if (wave < 4){
        int rr = (wave - 2) * 16 + srow;
        gload16(Bt + (size_t)rr * 2048 + 1024 + k0 + skoff, &tBl[(wave - 2) * 512]);
      }
      __syncthreads();
      short8 af[2], bh[2], bl[2];
      #pragma unroll
      for (int m = 0; m < 2; ++m)
        af[m] = *(const short8*)&tA[(wave * 32 + m * 16 + l15) * 32 + l4 * 8];
      #pragma unroll
      for (int n = 0; n < 2; ++n){
        bh[n] = *(const short8*)&tBh[(n * 16 + l15) * 32 + l4 * 8];
        bl[n] = *(const short8*)&tBl[(n * 16 + l15) * 32 + l4 * 8];
      }
      #pragma unroll
      for (int m = 0; m < 2; ++m)
        #pragma unroll
        for (int n = 0; n < 2; ++n){
          acc[m][n] = __builtin_amdgcn_mfma_f32_16x16x32_bf16(af[m], bh[n], acc[m][n], 0, 0, 0);
          acc[m][n] = __builtin_amdgcn_mfma_f32_16x16x32_bf16(af[m], bl[n], acc[m][n], 0, 0, 0);
        }
      __syncthreads();
    }
    #pragma unroll
    for (int n = 0; n < 2; ++n){
      int col = n * 16 + l15;
      #pragma unroll
      for (int m = 0; m < 2; ++m){
        int rowb = m0 + wave * 32 + m * 16 + l4 * 4;
        #pragma unroll
        for (int r = 0; r < 4; ++r)
          dtr[(size_t)(rowb + r) * 32 + col] = acc[m][n][r];
      }
    }
    return;
  }

  // ---------------- gemm path (R6/R7 verified schedule) ----------------
  const int wr = wave >> 2, wc = wave & 3;
  const int cpx = GEMM_NB >> 3;
  const int swz = (bid & 7) * cpx + (bid >> 3);
  const int m0 = (swz / nbx) * 256, n0 = (swz % nbx) * 256;

  const int stage_eg = ((tid & 7) * 8) ^ (((tid >> 3) & 7) << 3);
  const int e0 = (l4 * 8) ^ ((l15 & 7) << 3);
  const int e1 = (32 + l4 * 8) ^ ((l15 & 7) << 3);
  const int aoff_base = wr * 8192 + l15 * 64;
  const int boff_base = 16384 + (wc >> 1) * 8192 + ((wc & 1) * 64 + l15) * 64;

  auto stage = [&](int t, int isB, int h, int dbuf){
    if (t < 16){
      const ushort_t* src = isB ? Bt : A;
      const int row0 = (isB ? n0 : m0) + h * 128 + (tid >> 3);
      const int dst = dbuf * 32768 + isB * 16384 + h * 8192 + tid * 8;
      gload16(src + (size_t)row0 * 1024 + t * 64 + stage_eg, &lds[dst]);
      gload16(src + (size_t)(row0 + 64) * 1024 + t * 64 + stage_eg, &lds[dst + 4096]);
    }
  };

  f32x4 acc[8][4];
  #pragma unroll
  for (int m = 0; m < 8; ++m)
    #pragma unroll
    for (int n = 0; n < 4; ++n)
      #pragma unroll
      for (int r = 0; r < 4; ++r) acc[m][n][r] = 0.f;

  stage(0, 1, 0, 0); stage(0, 1, 1, 0);
  stage(0, 0, 0, 0); stage(0, 0, 1, 0);
  stage(1, 1, 0, 1); stage(1, 1, 1, 1);
  asm volatile("s_waitcnt vmcnt(4)" ::: "memory");
  BAR();

  short8 aF[4][2], bK[2][2], bF[2][2];

  for (int i = 0; i < 8; ++i){
    #pragma unroll
    for (int hh = 0; hh < 2; ++hh){
      const int bufo = hh * 32768;
      const int tA_ = (hh == 0) ? 2 * i + 1 : 2 * i + 2;
      const int dbA = (hh == 0) ? 1 : 0;
      const int tB_ = (hh == 0) ? 2 * i + 2 : 2 * i + 3;
      const int dbB = (hh == 0) ? 0 : 1;
      const int ao = bufo + aoff_base;
      const int bo = bufo + boff_base;
      // ph1: read A m0-3 + B n0-1 ; stage A0
      #pragma unroll
      for (int m = 0; m < 4; ++m){
        aF[m][0] = *(const short8*)&lds[ao + m * 1024 + e0];
        aF[m][1] = *(const short8*)&lds[ao + m * 1024 + e1];
      }
      #pragma unroll
      for (int n = 0; n < 2; ++n){
        bK[n][0] = *(const short8*)&lds[bo + n * 1024 + e0];
        bK[n][1] = *(const short8*)&lds[bo + n * 1024 + e1];
      }
      stage(tA_, 0, 0, dbA);
      BAR();
      __builtin_amdgcn_s_setprio(1);
      #pragma unroll
      for (int m = 0; m < 4; ++m)
        #pragma unroll
        for (int n = 0; n < 2; ++n){
          acc[m][n] = __builtin_amdgcn_mfma_f32_16x16x32_bf16(aF[m][0], bK[n][0], acc[m][n], 0, 0, 0);
          acc[m][n] = __builtin_amdgcn_mfma_f32_16x16x32_bf16(aF[m][1], bK[n][1], acc[m][n], 0, 0, 0);
        }
      __builtin_amdgcn_s_setprio(0);
      BAR();
      // ph2: read B n2-3 ; stage A1
      #pragma unroll
      for (int n = 0; n < 2; ++n){
        bF[n][0] = *(const short8*)&lds[bo + (n + 2) * 1024 + e0];
        bF[n][1] = *(const short8*)&lds[bo + (n + 2) * 1024 + e1];
      }
      stage(tA_, 0, 1, dbA);
      BAR();
      __builtin_amdgcn_s_setprio(1);
      #pragma unroll
      for (int m = 0; m < 4; ++m)
        #pragma unroll
        for (int n = 0; n < 2; ++n){
          acc[m][n + 2] = __builtin_amdgcn_mfma_f32_16x16x32_bf16(aF[m][0], bF[n][0], acc[m][n + 2], 0, 0, 0);
          acc[m][n + 2] = __builtin_amdgcn_mfma_f32_16x16x32_bf16(aF[m][1], bF[n][1], acc[m][n + 2], 0, 0, 0);
        }
      __builtin_amdgcn_s_setprio(0);
      BAR();
      // ph3: read A m4-7 ; stage B0
      #pragma unroll
      for (int m = 0; m < 4; ++m){
        aF[m][0] = *(const short8*)&lds[ao + (m + 4) * 1024 + e0];
        aF[m][1] = *(const short8*)&lds[ao + (m + 4) * 1024 + e1];
      }
      stage(tB_, 1, 0, dbB);
      BAR();
      __builtin_amdgcn_s_setprio(1);
      #pragma unroll
      for (int m = 0; m < 4; ++m)
        #pragma unroll
        for (int n = 0; n < 2; ++n){
          acc[m + 4][n + 2] = __builtin_amdgcn_mfma_f32_16x16x32_bf16(aF[m][0], bF[n][0], acc[m + 4][n + 2], 0, 0, 0);
          acc[m + 4][n + 2] = __builtin_amdgcn_mfma_f32_16x16x32_bf16(aF[m][1], bF[n][1], acc[m + 4][n + 2], 0, 0, 0);
        }
      __builtin_amdgcn_s_setprio(0);
      BAR();
      // ph4: no reads ; stage B1 ; counted vm wait
      stage(tB_, 1, 1, dbB);
      BAR();
      __builtin_amdgcn_s_setprio(1);
      #pragma unroll
      for (int m = 0; m < 4; ++m)
        #pragma unroll
        for (int n = 0; n < 2; ++n){
          acc[m + 4][n] = __builtin_amdgcn_mfma_f32_16x16x32_bf16(aF[m][0], bK[n][0], acc[m + 4][n], 0, 0, 0);
          acc[m + 4][n] = __builtin_amdgcn_mfma_f32_16x16x32_bf16(aF[m][1], bK[n][1], acc[m + 4][n], 0, 0, 0);
        }
      __builtin_amdgcn_s_setprio(0);
      asm volatile("s_waitcnt vmcnt(4)" ::: "memory");
      BAR();
    }
  }

  #pragma unroll
  for (int m = 0; m < 8; ++m){
    const int row = m0 + wr * 128 + m * 16 + l4 * 4;
    #pragma unroll
    for (int n = 0; n < 4; ++n){
      const int col = n0 + wc * 64 + n * 16 + l15;
      #pragma unroll
      for (int r = 0; r < 4; ++r)
        C[(size_t)(row + r) * N + col] = f2bf(acc[m][n][r]);
    }
  }
}

// ---------------- 128^2 bf16 MFMA GEMM (GEMM1) ----------------
__global__ __launch_bounds__(256)
void k_gemm_bf16(const ushort_t* __restrict__ A, const ushort_t* __restrict__ Bt,
                 const float* __restrict__ bias, ushort_t* __restrict__ C,
                 int K, int N, int nbx){
  __shared__ ushort_t tA[128 * 32];
  __shared__ ushort_t tB[128 * 32];
  const int nwg = gridDim.x;
  const int cpx = nwg >> 3;
  const int bid = blockIdx.x;
  const int swz = (bid & 7) * cpx + (bid >> 3);
  const int m0 = (swz / nbx) * 128, n0 = (swz % nbx) * 128;

  const int tid  = threadIdx.x;
  const int wave = tid >> 6, lane = tid & 63;
  const int wr = wave >> 1, wc = wave & 1;
  const int l15 = lane & 15, l4 = lane >> 4;
  const int srow  = lane >> 2;
  const int skoff = (lane & 3) * 8;

  f32x4 acc[4][4];
  #pragma unroll
  for (int m = 0; m < 4; ++m)
    #pragma unroll
    for (int n = 0; n < 4; ++n)
      #pragma unroll
      for (int r = 0; r < 4; ++r) acc[m][n][r] = 0.f;

  for (int k0 = 0; k0 < K; k0 += 32){
    #pragma unroll
    for (int r = 0; r < 2; ++r){
      int chunk = r * 4 + wave;
      int rr = chunk * 16 + srow;
      gload16(A  + (size_t)(m0 + rr) * K + k0 + skoff, &tA[chunk * 512]);
      gload16(Bt + (size_t)(n0 + rr) * K + k0 + skoff, &tB[chunk * 512]);
    }
    __syncthreads();
    short8 af[4], bfv[4];
    #pragma unroll
    for (int m = 0; m < 4; ++m)
      af[m] = *(const short8*)&tA[(wr * 64 + m * 16 + l15) * 32 + l4 * 8];
    #pragma unroll
    for (int n = 0; n < 4; ++n)
      bfv[n] = *(const short8*)&tB[(wc * 64 + n * 16 + l15) * 32 + l4 * 8];
    #pragma unroll
    for (int m = 0; m < 4; ++m)
      #pragma unroll
      for (int n = 0; n < 4; ++n)
        acc[m][n] = __builtin_amdgcn_mfma_f32_16x16x32_bf16(af[m], bfv[n], acc[m][n], 0, 0, 0);
    __syncthreads();
  }
  #pragma unroll
  for (int n = 0; n < 4; ++n){
    int col = n0 + wc * 64 + n * 16 + l15;
    float bv = bias ? bias[col] : 0.f;
    #pragma unroll
    for (int m = 0; m < 4; ++m){
      int rowb = m0 + wr * 64 + m * 16 + l4 * 4;
      #pragma unroll
      for (int r = 0; r < 4; ++r)
        C[(size_t)(rowb + r) * N + col] = f2bf(acc[m][n][r] + bv);
    }
  }
}

// ---------------- fused conv(B,C)+g: g[b,t] = silu(conv xbc)[t,2048:2176] . C_last ----------------
__global__ __launch_bounds__(256)
void k_bcg(const ushort_t* __restrict__ xbc, const float* __restrict__ conv_w,
           const float* __restrict__ conv_b, float* __restrict__ g){
  __shared__ float csh[128];
  const int b = blockIdx.y;
  const int t0 = blockIdx.x * 256;
  const int tid = threadIdx.x;
  const size_t rowb = (size_t)b * 2048;

  if (tid < 128){                 // recompute C_last (t=2047, cols 2176:2304)
    int c = 2176 + tid;
    f32x4 w4 = *(const f32x4*)&conv_w[c * 4];
    float a = conv_b[c];
    #pragma unroll
    for (int k = 0; k < 4; ++k)
      a += bf2f(xbc[(rowb + 2044 + k) * 2304 + c]) * w4[k];
    csh[tid] = a / (1.f + __expf(-a));
  }
  __syncthreads();

  const int t = t0 + tid;
  float gacc = 0.f;
  #pragma unroll 2
  for (int c8 = 0; c8 < 16; ++c8){
    const int cbase = 2048 + c8 * 8;
    short8 v[4];
    #pragma unroll
    for (int k = 0; k < 4; ++k){
      int tt = t - 3 + k;
      if (tt >= 0) v[k] = *(const short8*)&xbc[(rowb + tt) * 2304 + cbase];
      else { short8 z = {0,0,0,0,0,0,0,0}; v[k] = z; }
    }
    #pragma unroll
    for (int j = 0; j < 8; ++j){
      int c = cbase + j;
      f32x4 w4 = *(const f32x4*)&conv_w[c * 4];
      float a = conv_b[c];
      #pragma unroll
      for (int k = 0; k < 4; ++k) a += bf2f((ushort_t)v[k][j]) * w4[k];
      float s = a / (1.f + __expf(-a));
      gacc += s * csh[c8 * 8 + j];
    }
  }
  g[rowb + t] = gacc;
}

// ---------------- per-(b,h) suffix scan -> coeff ----------------
__global__ void k_coeff(const float* __restrict__ dt_raw, const float* __restrict__ dt_bias,
                        const float* __restrict__ A_log, const float* __restrict__ g,
                        float* __restrict__ coeffw){
  __shared__ float csum[256];
  int bh = blockIdx.x;
  int b = bh >> 5, h = bh & 31;
  float Ah = -__expf(A_log[h]);
  float bias = dt_bias[h];
  int tid = threadIdx.x;
  size_t base = (size_t)b * 2048;
  float d[8], dts[8];
  #pragma unroll
  for (int j = 0; j < 8; ++j){
    int t = tid * 8 + j;
    float x = dt_raw[(base + t) * 32 + h] + bias;
    float sp = (x > 20.f) ? x : log1pf(__expf(x));
    dts[j] = sp;
    d[j] = sp * Ah;
  }
  float cs = 0.f;
  #pragma unroll
  for (int j = 0; j < 8; ++j) cs += d[j];
  csum[tid] = cs;
  __syncthreads();
  float suf = 0.f;
  for (int j = tid + 1; j < 256; ++j) suf += csum[j];
  float S = suf, outv[8];
  for (int j = 7; j >= 0; --j){ outv[j] = S; S += d[j]; }
  #pragma unroll
  for (int j = 0; j < 8; ++j){
    int t = tid * 8 + j;
    coeffw[(size_t)bh * 2048 + t] = __expf(outv[j]) * dts[j] * g[base + t];
  }
}

// ---------------- fused conv(x-part)+SiLU+weighted time-sum ----------------
__global__ __launch_bounds__(256)
void k_ysum2f(const float* __restrict__ coeffw, const ushort_t* __restrict__ xbc,
              const float* __restrict__ conv_w, const float* __restrict__ conv_b,
              float* __restrict__ ypart2, ushort_t* __restrict__ xhlast){
  int b = blockIdx.x, ch = blockIdx.y;
  int tid = threadIdx.x;
  int c0 = tid * 8;
  int h = tid >> 3;
  int t0 = ch * 32;
  const float* cwt = coeffw + ((size_t)(b * 32 + h)) * 2048 + t0;
  const size_t rowbase = (size_t)b * 2048;

  float wv[8][4], cb[8];
  #pragma unroll
  for (int j = 0; j < 8; ++j){
    f32x4 w4 = *(const f32x4*)&conv_w[(c0 + j) * 4];
    #pragma unroll
    for (int k = 0; k < 4; ++k) wv[j][k] = w4[k];
    cb[j] = conv_b[c0 + j];
  }
  float h0[8], h1[8], h2[8];
  {
    float* hs[3] = {h0, h1, h2};
    #pragma unroll
    for (int k = 0; k < 3; ++k){
      int tt = t0 - 3 + k;
      if (tt >= 0){
        short8 v = *(const short8*)&xbc[(rowbase + tt) * 2304 + c0];
        #pragma unroll
        for (int j = 0; j < 8; ++j) hs[k][j] = bf2f((ushort_t)v[j]);
      } else {
        #pragma unroll
        for (int j = 0; j < 8; ++j) hs[k][j] = 0.f;
      }
    }
  }
  float acc[8] = {0.f, 0.f, 0.f, 0.f, 0.f, 0.f, 0.f, 0.f};
  float sil[8];
  for (int t = 0; t < 32; ++t){
    short8 v = *(const short8*)&xbc[(rowbase + t0 + t) * 2304 + c0];
    float cf = cwt[t];
    #pragma unroll
    for (int j = 0; j < 8; ++j){
      float xv = bf2f((ushort_t)v[j]);
      float a = cb[j] + h0[j] * wv[j][0] + h1[j] * wv[j][1] + h2[j] * wv[j][2] + xv * wv[j][3];
      float s = a / (1.f + __expf(-a));
      sil[j] = s;
      acc[j] += cf * s;
      h0[j] = h1[j]; h1[j] = h2[j]; h2[j] = xv;
    }
  }
  float* op = ypart2 + (((size_t)b * 64 + ch) * 2048) + c0;
  f32x4 o0, o1;
  #pragma unroll
  for (int j = 0; j < 4; ++j){ o0[j] = acc[j]; o1[j] = acc[4 + j]; }
  *(f32x4*)op = o0;
  *(f32x4*)(op + 4) = o1;
  if (ch == 63){
    ushort4v s0, s1;
    #pragma unroll
    for (int j = 0; j < 4; ++j){ s0[j] = f2bf(sil[j]); s1[j] = f2bf(sil[4 + j]); }
    *(ushort4v*)&xhlast[b * 2048 + c0] = s0;
    *(ushort4v*)&xhlast[b * 2048 + c0 + 4] = s1;
  }
}

// ---------------- fused ypart-reduce + D-term + gated RMSNorm ----------------
__global__ __launch_bounds__(256)
void k_norm2(const float* __restrict__ ypart2, const ushort_t* __restrict__ xhlast,
             const float* __restrict__ Dp, const float* __restrict__ z_last,
             const float* __restrict__ norm_w, float* __restrict__ yn){
  __shared__ float red[256];
  int b = blockIdx.x, tid = threadIdx.x;
  float vals[8], ss = 0.f;
  #pragma unroll
  for (int j = 0; j < 8; ++j){
    int c = tid + 256 * j;
    float v = 0.f;
    #pragma unroll 8
    for (int ch = 0; ch < 64; ++ch)
      v += ypart2[(((size_t)b * 64 + ch) << 11) + c];
    v += Dp[c >> 6] * bf2f(xhlast[b * 2048 + c]);
    float z = z_last[b * 2048 + c];
    float yg = v * (z / (1.f + __expf(-z)));
    vals[j] = yg; ss += yg * yg;
  }
  red[tid] = ss; __syncthreads();
  for (int s = 128; s; s >>= 1){
    if (tid < s) red[tid] += red[tid + s];
    __syncthreads();
  }
  float scale = rsqrtf(red[0] / 2048.f + EPSV);
  #pragma unroll
  for (int j = 0; j < 8; ++j){
    int c = tid + 256 * j;
    yn[b * 2048 + c] = vals[j] * scale * norm_w[c];
  }
}

// ---------------- out projection: wave per column ----------------
__global__ __launch_bounds__(64)
void k_outproj(const float* __restrict__ yn, const float* __restrict__ wot,
               float* __restrict__ o){
  int col = blockIdx.x;
  int l = threadIdx.x;
  float acc[8] = {0.f, 0.f, 0.f, 0.f, 0.f, 0.f, 0.f, 0.f};
  const float* wp = wot + (size_t)col * 2048;
  #pragma unroll 4
  for (int i = 0; i < 32; ++i){
    int k = i * 64 + l;
    float w = wp[k];
    #pragma unroll
    for (int b = 0; b < 8; ++b)
      acc[b] += yn[b * 2048 + k] * w;
  }
  #pragma unroll
  for (int b = 0; b < 8; ++b){
    float v = acc[b];
    for (int s = 32; s; s >>= 1) v += __shfl_down(v, s, 64);
    if (l == 0) o[b * 1024 + col] = v;
  }
}

// ---------------- head: wave per output column ----------------
__global__ __launch_bounds__(64)
void k_head(const float* __restrict__ o, const float* __restrict__ wht,
            const float* __restrict__ b_head, float* __restrict__ out){
  int j = blockIdx.x;
  int l = threadIdx.x;
  float acc[8] = {0.f, 0.f, 0.f, 0.f, 0.f, 0.f, 0.f, 0.f};
  const float* wp = wht + (size_t)j * 1024;
  #pragma unroll 4
  for (int i = 0; i < 16; ++i){
    int k = i * 64 + l;
    float w = wp[k];
    #pragma unroll
    for (int b = 0; b < 8; ++b)
      acc[b] += o[b * 1024 + k] * w;
  }
  #pragma unroll
  for (int b = 0; b < 8; ++b){
    float v = acc[b];
    for (int s = 32; s; s >>= 1) v += __shfl_down(v, s, 64);
    if (l == 0) out[b * 64 + j] = v + b_head[j];
  }
}

extern "C" void kernel_launch(void* const* d_in, const int* in_sizes, int n_in,
                              void* d_out, int out_size, void* d_ws, size_t ws_size,
                              hipStream_t stream){
  (void)in_sizes; (void)n_in; (void)out_size; (void)ws_size;
  const float* x       = (const float*)d_in[0];
  const float* w_proj  = (const float*)d_in[1];
  const float* b_proj  = (const float*)d_in[2];
  const float* w_in    = (const float*)d_in[3];
  const float* conv_w  = (const float*)d_in[4];
  const float* conv_b  = (const float*)d_in[5];
  const float* A_log   = (const float*)d_in[6];
  const float* dt_bias = (const float*)d_in[7];
  const float* Dp      = (const float*)d_in[8];
  const float* norm_w  = (const float*)d_in[9];
  const float* w_out   = (const float*)d_in[10];
  const float* w_head  = (const float*)d_in[11];
  const float* b_head  = (const float*)d_in[12];
  float* out = (float*)d_out;

  char* ws = (char*)d_ws;
  size_t off = 0;
  auto alloc = [&](size_t bytes)->char*{
    char* p = ws + off; off += (bytes + 255) & ~(size_t)255; return p;
  };
  ushort_t* xb    = (ushort_t*)alloc((size_t)M_ROWS * 64 * 2);
  ushort_t* w1t   = (ushort_t*)alloc((size_t)1024 * 64 * 2);
  ushort_t* w2t   = (ushort_t*)alloc((size_t)2304 * 1024 * 2);
  ushort_t* wdt   = (ushort_t*)alloc((size_t)32 * 2048 * 2);
  float*    wzT   = (float*)alloc((size_t)2048 * 1024 * 4);
  float*    wot   = (float*)alloc((size_t)1024 * 2048 * 4);
  float*    wht   = (float*)alloc((size_t)64 * 1024 * 4);
  ushort_t* u16   = (ushort_t*)alloc((size_t)M_ROWS * 1024 * 2);
  ushort_t* xbc   = (ushort_t*)alloc((size_t)M_ROWS * 2304 * 2);
  float*    dtr   = (float*)alloc((size_t)M_ROWS * 32 * 4);
  float*    g     = (float*)alloc((size_t)M_ROWS * 4);
  float*    cfw   = (float*)alloc((size_t)256 * 2048 * 4);
  float*    ypart = (float*)alloc((size_t)8 * 64 * 2048 * 4);
  ushort_t* xhl   = (ushort_t*)alloc((size_t)8 * 2048 * 2);
  float*    zl    = (float*)alloc((size_t)8 * 2048 * 4);
  float*    yn    = (float*)alloc((size_t)8 * 2048 * 4);
  float*    ov    = (float*)alloc((size_t)8 * 1024 * 4);

  k_prep<<<6096, 256, 0, stream>>>(x, w_proj, w_in, w_out, w_head,
                                   xb, w1t, w2t, wdt, wzT, wot, wht);

  k_gemm_bf16<<<(1024 / 128) * (M_ROWS / 128), 256, 0, stream>>>(xb, w1t, b_proj, u16, 64, 1024, 1024 / 128);

  k_fused256<<<GEMM_NB + DTG_NB + ZL_NB, 512, 0, stream>>>(u16, w2t, xbc, wdt, dtr, wzT, zl, 2304, 2304 / 256);

  dim3 gbc(8, 8);
  k_bcg<<<gbc, 256, 0, stream>>>(xbc, conv_w, conv_b, g);

  k_coeff<<<256, 256, 0, stream>>>(dtr, dt_bias, A_log, g, cfw);

  dim3 gy(8, 64);
  k_ysum2f<<<gy, 256, 0, stream>>>(cfw, xbc, conv_w, conv_b, ypart, xhl);

  k_norm2<<<8, 256, 0, stream>>>(ypart, xhl, Dp, zl, norm_w, yn);
  k_outproj<<<1024, 64, 0, stream>>>(yn, wot, ov);
  k_head<<<64, 64, 0, stream>>>(ov, wht, b_head, out);
}

// Round 9
// 206.014 us; speedup vs baseline: 1.1456x; 1.1456x over previous
//
#include <hip/hip_runtime.h>
#include <hip/hip_bf16.h>
#include <stdint.h>

typedef unsigned short ushort_t;
typedef __attribute__((ext_vector_type(8))) short short8;
typedef __attribute__((ext_vector_type(4))) short short4v;
typedef __attribute__((ext_vector_type(4))) unsigned short ushort4v;
typedef __attribute__((ext_vector_type(4))) float f32x4;

#define L_SEQ   2048
#define BATCH   8
#define M_ROWS  16384          // BATCH*L_SEQ
#define EPSV    1e-5f
#define GEMM_NB 576            // 64 m-tiles x 9 n-tiles
#define DTG_NB  64             // 64 blocks x 256 rows
#define ZL_NB   256            // 256 blocks x 8 cols

__device__ __forceinline__ float bf2f(ushort_t u){
  union { uint32_t i; float f; } v; v.i = ((uint32_t)u) << 16; return v.f;
}
__device__ __forceinline__ ushort_t f2bf(float f){
  union { float f; uint32_t i; } v; v.f = f;
  uint32_t r = v.i + 0x7fffu + ((v.i >> 16) & 1u);
  return (ushort_t)(r >> 16);
}

// ---------------- fused prep: cvt + w1t + wdt + 4 transposes ----------------
__global__ __launch_bounds__(256)
void k_prep(const float* __restrict__ x, const float* __restrict__ w_proj,
            const float* __restrict__ w_in, const float* __restrict__ w_out,
            const float* __restrict__ w_head,
            ushort_t* __restrict__ xb, ushort_t* __restrict__ w1t,
            ushort_t* __restrict__ w2t, ushort_t* __restrict__ wdt,
            float* __restrict__ wzT, float* __restrict__ wot, float* __restrict__ wht){
  __shared__ float tile[64][65];
  int bx = blockIdx.x, tid = threadIdx.x;
  if (bx < 4096){                          // x -> bf16
    int i = bx * 256 + tid;
    xb[i] = f2bf(x[i]);
    return;
  }
  bx -= 4096;
  if (bx < 256){                           // w1t[j*64+k] = w_proj[k*1024+j]
    int i = bx * 256 + tid; int k = i >> 10, j = i & 1023;
    w1t[j * 64 + k] = f2bf(w_proj[i]);
    return;
  }
  bx -= 256;
  if (bx < 128){                           // dt weights hi/lo split
    int i = bx * 256 + tid; int n = i >> 10, k = i & 1023;
    float w = w_in[(size_t)k * 4384 + 4352 + n];
    ushort_t hi = f2bf(w);
    wdt[n * 2048 + k] = hi;
    wdt[n * 2048 + 1024 + k] = f2bf(w - bf2f(hi));
    return;
  }
  bx -= 128;
  const float* src; float* dstf = nullptr; ushort_t* dstb = nullptr;
  int R, C, colOff, j0, k0;
  if (bx < 576){       src = w_in;   dstb = w2t; R = 1024; C = 4384; colOff = 2048; j0 = (bx % 36) * 64; k0 = (bx / 36) * 64; }
  else if ((bx -= 576) < 512){ src = w_in;  dstf = wzT; R = 1024; C = 4384; colOff = 0; j0 = (bx % 32) * 64; k0 = (bx / 32) * 64; }
  else if ((bx -= 512) < 512){ src = w_out; dstf = wot; R = 2048; C = 1024; colOff = 0; j0 = (bx % 16) * 64; k0 = (bx / 16) * 64; }
  else { bx -= 512;    src = w_head; dstf = wht; R = 1024; C = 64;   colOff = 0; j0 = 0;             k0 = bx * 64; }
  int tx = tid & 63, ty = tid >> 6;
  #pragma unroll
  for (int i = 0; i < 16; ++i){
    int kk = ty * 16 + i;
    tile[kk][tx] = src[(size_t)(k0 + kk) * C + colOff + j0 + tx];
  }
  __syncthreads();
  #pragma unroll
  for (int i = 0; i < 16; ++i){
    int jj = ty * 16 + i;
    if (dstb) dstb[(size_t)(j0 + jj) * R + k0 + tx] = f2bf(tile[tx][jj]);
    else      dstf[(size_t)(j0 + jj) * R + k0 + tx] = tile[tx][jj];
  }
}

// ---------------- async global->LDS ----------------
__device__ __forceinline__ void gload16(const void* g, void* l){
  __builtin_amdgcn_global_load_lds((const __attribute__((address_space(1))) void*)g,
                                   (__attribute__((address_space(3))) void*)l, 16, 0, 0);
}
__device__ __forceinline__ void BAR(){
  asm volatile("" ::: "memory");
  __builtin_amdgcn_s_barrier();
  asm volatile("" ::: "memory");
}

// ---------------- fused: 256x256 8-phase GEMM2 + dtg + zlast ----------------
__global__ __launch_bounds__(512, 1)
void k_fused256(const ushort_t* __restrict__ A, const ushort_t* __restrict__ Bt,
                ushort_t* __restrict__ C, const ushort_t* __restrict__ wdt,
                float* __restrict__ dtr, const float* __restrict__ wzT,
                float* __restrict__ z_last, int N, int nbx){
  __shared__ ushort_t lds[65536];
  const int bid = blockIdx.x;
  const int tid = threadIdx.x;
  const int lane = tid & 63;
  const int wave = tid >> 6;
  const int l15 = lane & 15, l4 = lane >> 4;

  if (bid >= GEMM_NB + DTG_NB){
    // ---------------- z_last: 8 waves, wave per column ----------------
    int col = (bid - GEMM_NB - DTG_NB) * 8 + wave;
    float acc[8] = {0.f, 0.f, 0.f, 0.f, 0.f, 0.f, 0.f, 0.f};
    const float* wp = wzT + (size_t)col * 1024;
    #pragma unroll 4
    for (int i = 0; i < 16; ++i){
      int k = i * 64 + lane;
      float w = wp[k];
      #pragma unroll
      for (int b = 0; b < 8; ++b)
        acc[b] += bf2f(A[((size_t)b * 2048 + 2047) * 1024 + k]) * w;
    }
    #pragma unroll
    for (int b = 0; b < 8; ++b){
      float v = acc[b];
      for (int s = 32; s; s >>= 1) v += __shfl_down(v, s, 64);
      if (lane == 0) z_last[b * 2048 + col] = v;
    }
    return;
  }

  if (bid >= GEMM_NB){
    // ---------------- dt GEMM: 256 rows/block, 8 waves ----------------
    const int m0 = (bid - GEMM_NB) * 256;
    ushort_t* tA  = lds;            // 256*32
    ushort_t* tBh = lds + 8192;     // 32*32
    ushort_t* tBl = lds + 9216;     // 32*32
    const int srow  = lane >> 2;
    const int skoff = (lane & 3) * 8;
    f32x4 acc[2][2];
    #pragma unroll
    for (int m = 0; m < 2; ++m)
      #pragma unroll
      for (int n = 0; n < 2; ++n)
        #pragma unroll
        for (int r = 0; r < 4; ++r) acc[m][n][r] = 0.f;
    for (int k0 = 0; k0 < 1024; k0 += 32){
      #pragma unroll
      for (int r = 0; r < 2; ++r){
        int chunk = r * 8 + wave;
        int rr = chunk * 16 + srow;
        gload16(A + (size_t)(m0 + rr) * 1024 + k0 + skoff, &tA[chunk * 512]);
      }
      if (wave < 2){
        int rr = wave * 16 + srow;
        gload16(Bt + (size_t)rr * 2048 + k0 + skoff, &tBh[wave * 512]);
      } else if (wave < 4){
        int rr = (wave - 2) * 16 + srow;
        gload16(Bt + (size_t)rr * 2048 + 1024 + k0 + skoff, &tBl[(wave - 2) * 512]);
      }
      __syncthreads();
      short8 af[2], bh[2], bl[2];
      #pragma unroll
      for (int m = 0; m < 2; ++m)
        af[m] = *(const short8*)&tA[(wave * 32 + m * 16 + l15) * 32 + l4 * 8];
      #pragma unroll
      for (int n = 0; n < 2; ++n){
        bh[n] = *(const short8*)&tBh[(n * 16 + l15) * 32 + l4 * 8];
        bl[n] = *(const short8*)&tBl[(n * 16 + l15) * 32 + l4 * 8];
      }
      #pragma unroll
      for (int m = 0; m < 2; ++m)
        #pragma unroll
        for (int n = 0; n < 2; ++n){
          acc[m][n] = __builtin_amdgcn_mfma_f32_16x16x32_bf16(af[m], bh[n], acc[m][n], 0, 0, 0);
          acc[m][n] = __builtin_amdgcn_mfma_f32_16x16x32_bf16(af[m], bl[n], acc[m][n], 0, 0, 0);
        }
      __syncthreads();
    }
    #pragma unroll
    for (int n = 0; n < 2; ++n){
      int col = n * 16 + l15;
      #pragma unroll
      for (int m = 0; m < 2; ++m){
        int rowb = m0 + wave * 32 + m * 16 + l4 * 4;
        #pragma unroll
        for (int r = 0; r < 4; ++r)
          dtr[(size_t)(rowb + r) * 32 + col] = acc[m][n][r];
      }
    }
    return;
  }

  // ---------------- gemm path (verified schedule) ----------------
  const int wr = wave >> 2, wc = wave & 3;
  const int cpx = GEMM_NB >> 3;
  const int swz = (bid & 7) * cpx + (bid >> 3);
  const int m0 = (swz / nbx) * 256, n0 = (swz % nbx) * 256;

  const int stage_eg = ((tid & 7) * 8) ^ (((tid >> 3) & 7) << 3);
  const int e0 = (l4 * 8) ^ ((l15 & 7) << 3);
  const int e1 = (32 + l4 * 8) ^ ((l15 & 7) << 3);
  const int aoff_base = wr * 8192 + l15 * 64;
  const int boff_base = 16384 + (wc >> 1) * 8192 + ((wc & 1) * 64 + l15) * 64;

  auto stage = [&](int t, int isB, int h, int dbuf){
    if (t < 16){
      const ushort_t* src = isB ? Bt : A;
      const int row0 = (isB ? n0 : m0) + h * 128 + (tid >> 3);
      const int dst = dbuf * 32768 + isB * 16384 + h * 8192 + tid * 8;
      gload16(src + (size_t)row0 * 1024 + t * 64 + stage_eg, &lds[dst]);
      gload16(src + (size_t)(row0 + 64) * 1024 + t * 64 + stage_eg, &lds[dst + 4096]);
    }
  };

  f32x4 acc[8][4];
  #pragma unroll
  for (int m = 0; m < 8; ++m)
    #pragma unroll
    for (int n = 0; n < 4; ++n)
      #pragma unroll
      for (int r = 0; r < 4; ++r) acc[m][n][r] = 0.f;

  stage(0, 1, 0, 0); stage(0, 1, 1, 0);
  stage(0, 0, 0, 0); stage(0, 0, 1, 0);
  stage(1, 1, 0, 1); stage(1, 1, 1, 1);
  asm volatile("s_waitcnt vmcnt(4)" ::: "memory");
  BAR();

  short8 aF[4][2], bK[2][2], bF[2][2];

  for (int i = 0; i < 8; ++i){
    #pragma unroll
    for (int hh = 0; hh < 2; ++hh){
      const int bufo = hh * 32768;
      const int tA_ = (hh == 0) ? 2 * i + 1 : 2 * i + 2;
      const int dbA = (hh == 0) ? 1 : 0;
      const int tB_ = (hh == 0) ? 2 * i + 2 : 2 * i + 3;
      const int dbB = (hh == 0) ? 0 : 1;
      const int ao = bufo + aoff_base;
      const int bo = bufo + boff_base;
      // ph1: read A m0-3 + B n0-1 ; stage A0
      #pragma unroll
      for (int m = 0; m < 4; ++m){
        aF[m][0] = *(const short8*)&lds[ao + m * 1024 + e0];
        aF[m][1] = *(const short8*)&lds[ao + m * 1024 + e1];
      }
      #pragma unroll
      for (int n = 0; n < 2; ++n){
        bK[n][0] = *(const short8*)&lds[bo + n * 1024 + e0];
        bK[n][1] = *(const short8*)&lds[bo + n * 1024 + e1];
      }
      stage(tA_, 0, 0, dbA);
      BAR();
      __builtin_amdgcn_s_setprio(1);
      #pragma unroll
      for (int m = 0; m < 4; ++m)
        #pragma unroll
        for (int n = 0; n < 2; ++n){
          acc[m][n] = __builtin_amdgcn_mfma_f32_16x16x32_bf16(aF[m][0], bK[n][0], acc[m][n], 0, 0, 0);
          acc[m][n] = __builtin_amdgcn_mfma_f32_16x16x32_bf16(aF[m][1], bK[n][1], acc[m][n], 0, 0, 0);
        }
      __builtin_amdgcn_s_setprio(0);
      BAR();
      // ph2: read B n2-3 ; stage A1
      #pragma unroll
      for (int n = 0; n < 2; ++n){
        bF[n][0] = *(const short8*)&lds[bo + (n + 2) * 1024 + e0];
        bF[n][1] = *(const short8*)&lds[bo + (n + 2) * 1024 + e1];
      }
      stage(tA_, 0, 1, dbA);
      BAR();
      __builtin_amdgcn_s_setprio(1);
      #pragma unroll
      for (int m = 0; m < 4; ++m)
        #pragma unroll
        for (int n = 0; n < 2; ++n){
          acc[m][n + 2] = __builtin_amdgcn_mfma_f32_16x16x32_bf16(aF[m][0], bF[n][0], acc[m][n + 2], 0, 0, 0);
          acc[m][n + 2] = __builtin_amdgcn_mfma_f32_16x16x32_bf16(aF[m][1], bF[n][1], acc[m][n + 2], 0, 0, 0);
        }
      __builtin_amdgcn_s_setprio(0);
      BAR();
      // ph3: read A m4-7 ; stage B0
      #pragma unroll
      for (int m = 0; m < 4; ++m){
        aF[m][0] = *(const short8*)&lds[ao + (m + 4) * 1024 + e0];
        aF[m][1] = *(const short8*)&lds[ao + (m + 4) * 1024 + e1];
      }
      stage(tB_, 1, 0, dbB);
      BAR();
      __builtin_amdgcn_s_setprio(1);
      #pragma unroll
      for (int m = 0; m < 4; ++m)
        #pragma unroll
        for (int n = 0; n < 2; ++n){
          acc[m + 4][n + 2] = __builtin_amdgcn_mfma_f32_16x16x32_bf16(aF[m][0], bF[n][0], acc[m + 4][n + 2], 0, 0, 0);
          acc[m + 4][n + 2] = __builtin_amdgcn_mfma_f32_16x16x32_bf16(aF[m][1], bF[n][1], acc[m + 4][n + 2], 0, 0, 0);
        }
      __builtin_amdgcn_s_setprio(0);
      BAR();
      // ph4: no reads ; stage B1 ; counted vm wait
      stage(tB_, 1, 1, dbB);
      BAR();
      __builtin_amdgcn_s_setprio(1);
      #pragma unroll
      for (int m = 0; m < 4; ++m)
        #pragma unroll
        for (int n = 0; n < 2; ++n){
          acc[m + 4][n] = __builtin_amdgcn_mfma_f32_16x16x32_bf16(aF[m][0], bK[n][0], acc[m + 4][n], 0, 0, 0);
          acc[m + 4][n] = __builtin_amdgcn_mfma_f32_16x16x32_bf16(aF[m][1], bK[n][1], acc[m + 4][n], 0, 0, 0);
        }
      __builtin_amdgcn_s_setprio(0);
      asm volatile("s_waitcnt vmcnt(4)" ::: "memory");
      BAR();
    }
  }

  #pragma unroll
  for (int m = 0; m < 8; ++m){
    const int row = m0 + wr * 128 + m * 16 + l4 * 4;
    #pragma unroll
    for (int n = 0; n < 4; ++n){
      const int col = n0 + wc * 64 + n * 16 + l15;
      #pragma unroll
      for (int r = 0; r < 4; ++r)
        C[(size_t)(row + r) * N + col] = f2bf(acc[m][n][r]);
    }
  }
}

// ---------------- 128^2 bf16 MFMA GEMM (GEMM1) ----------------
__global__ __launch_bounds__(256)
void k_gemm_bf16(const ushort_t* __restrict__ A, const ushort_t* __restrict__ Bt,
                 const float* __restrict__ bias, ushort_t* __restrict__ C,
                 int K, int N, int nbx){
  __shared__ ushort_t tA[128 * 32];
  __shared__ ushort_t tB[128 * 32];
  const int nwg = gridDim.x;
  const int cpx = nwg >> 3;
  const int bid = blockIdx.x;
  const int swz = (bid & 7) * cpx + (bid >> 3);
  const int m0 = (swz / nbx) * 128, n0 = (swz % nbx) * 128;

  const int tid  = threadIdx.x;
  const int wave = tid >> 6, lane = tid & 63;
  const int wr = wave >> 1, wc = wave & 1;
  const int l15 = lane & 15, l4 = lane >> 4;
  const int srow  = lane >> 2;
  const int skoff = (lane & 3) * 8;

  f32x4 acc[4][4];
  #pragma unroll
  for (int m = 0; m < 4; ++m)
    #pragma unroll
    for (int n = 0; n < 4; ++n)
      #pragma unroll
      for (int r = 0; r < 4; ++r) acc[m][n][r] = 0.f;

  for (int k0 = 0; k0 < K; k0 += 32){
    #pragma unroll
    for (int r = 0; r < 2; ++r){
      int chunk = r * 4 + wave;
      int rr = chunk * 16 + srow;
      gload16(A  + (size_t)(m0 + rr) * K + k0 + skoff, &tA[chunk * 512]);
      gload16(Bt + (size_t)(n0 + rr) * K + k0 + skoff, &tB[chunk * 512]);
    }
    __syncthreads();
    short8 af[4], bfv[4];
    #pragma unroll
    for (int m = 0; m < 4; ++m)
      af[m] = *(const short8*)&tA[(wr * 64 + m * 16 + l15) * 32 + l4 * 8];
    #pragma unroll
    for (int n = 0; n < 4; ++n)
      bfv[n] = *(const short8*)&tB[(wc * 64 + n * 16 + l15) * 32 + l4 * 8];
    #pragma unroll
    for (int m = 0; m < 4; ++m)
      #pragma unroll
      for (int n = 0; n < 4; ++n)
        acc[m][n] = __builtin_amdgcn_mfma_f32_16x16x32_bf16(af[m], bfv[n], acc[m][n], 0, 0, 0);
    __syncthreads();
  }
  #pragma unroll
  for (int n = 0; n < 4; ++n){
    int col = n0 + wc * 64 + n * 16 + l15;
    float bv = bias ? bias[col] : 0.f;
    #pragma unroll
    for (int m = 0; m < 4; ++m){
      int rowb = m0 + wr * 64 + m * 16 + l4 * 4;
      #pragma unroll
      for (int r = 0; r < 4; ++r)
        C[(size_t)(rowb + r) * N + col] = f2bf(acc[m][n][r] + bv);
    }
  }
}

// ---------------- conv+SiLU for B/C channels only (256 of 2304) ----------------
__global__ __launch_bounds__(256)
void k_convbc(const ushort_t* __restrict__ xbc, const float* __restrict__ conv_w,
              const float* __restrict__ conv_b, float* __restrict__ bmat,
              float* __restrict__ c_last){
  const int c0 = 2048 + (threadIdx.x & 63) * 4;
  const int tl = threadIdx.x >> 6;
  const int t0 = blockIdx.x * 64 + tl * 16;
  const int b  = blockIdx.y;
  const size_t rowbase = (size_t)b * 2048;

  float cw[4][4], cb[4];
  #pragma unroll
  for (int j = 0; j < 4; ++j){
    cb[j] = conv_b[c0 + j];
    f32x4 w4 = *(const f32x4*)&conv_w[(c0 + j) * 4];
    #pragma unroll
    for (int k = 0; k < 4; ++k) cw[j][k] = w4[k];
  }
  float h[3][4];
  #pragma unroll
  for (int k = 0; k < 3; ++k){
    int tt = t0 - 3 + k;
    if (tt >= 0){
      short4v v = *(const short4v*)&xbc[(rowbase + tt) * 2304 + c0];
      #pragma unroll
      for (int j = 0; j < 4; ++j) h[k][j] = bf2f((ushort_t)v[j]);
    } else {
      #pragma unroll
      for (int j = 0; j < 4; ++j) h[k][j] = 0.f;
    }
  }
  for (int t = t0; t < t0 + 16; ++t){
    short4v v = *(const short4v*)&xbc[(rowbase + t) * 2304 + c0];
    float outv[4];
    #pragma unroll
    for (int j = 0; j < 4; ++j){
      float x = bf2f((ushort_t)v[j]);
      float a = cb[j] + h[0][j] * cw[j][0] + h[1][j] * cw[j][1] + h[2][j] * cw[j][2] + x * cw[j][3];
      outv[j] = a / (1.f + __expf(-a));
      h[0][j] = h[1][j]; h[1][j] = h[2][j]; h[2][j] = x;
    }
    if (c0 < 2176){
      f32x4 o;
      #pragma unroll
      for (int j = 0; j < 4; ++j) o[j] = outv[j];
      *(f32x4*)&bmat[(rowbase + t) * 128 + (c0 - 2048)] = o;
    } else if (t == 2047){
      f32x4 o;
      #pragma unroll
      for (int j = 0; j < 4; ++j) o[j] = outv[j];
      *(f32x4*)&c_last[b * 128 + (c0 - 2176)] = o;
    }
  }
}

// ---------------- g[b,t] = B_t . C_last ----------------
__global__ void k_gdot(const float* __restrict__ bmat, const float* __restrict__ c_last,
                       float* __restrict__ g){
  int r = threadIdx.x >> 5, n = threadIdx.x & 31;
  int row = blockIdx.x * 8 + r;
  int b = row >> 11;
  const float* bp = bmat + (size_t)row * 128;
  const float* cp = c_last + b * 128;
  float acc = 0.f;
  #pragma unroll
  for (int j = 0; j < 4; ++j) acc += bp[n + 32 * j] * cp[n + 32 * j];
  for (int s = 16; s; s >>= 1) acc += __shfl_down(acc, s, 32);
  if (n == 0) g[row] = acc;
}

// ---------------- per-(b,h) suffix scan -> coeff ----------------
__global__ void k_coeff(const float* __restrict__ dt_raw, const float* __restrict__ dt_bias,
                        const float* __restrict__ A_log, const float* __restrict__ g,
                        float* __restrict__ coeffw){
  __shared__ float csum[256];
  int bh = blockIdx.x;
  int b = bh >> 5, h = bh & 31;
  float Ah = -__expf(A_log[h]);
  float bias = dt_bias[h];
  int tid = threadIdx.x;
  size_t base = (size_t)b * 2048;
  float d[8], dts[8];
  #pragma unroll
  for (int j = 0; j < 8; ++j){
    int t = tid * 8 + j;
    float x = dt_raw[(base + t) * 32 + h] + bias;
    float sp = (x > 20.f) ? x : log1pf(__expf(x));
    dts[j] = sp;
    d[j] = sp * Ah;
  }
  float cs = 0.f;
  #pragma unroll
  for (int j = 0; j < 8; ++j) cs += d[j];
  csum[tid] = cs;
  __syncthreads();
  float suf = 0.f;
  for (int j = tid + 1; j < 256; ++j) suf += csum[j];
  float S = suf, outv[8];
  for (int j = 7; j >= 0; --j){ outv[j] = S; S += d[j]; }
  #pragma unroll
  for (int j = 0; j < 8; ++j){
    int t = tid * 8 + j;
    coeffw[(size_t)bh * 2048 + t] = __expf(outv[j]) * dts[j] * g[base + t];
  }
}

// ---------------- fused conv(x-part)+SiLU+weighted time-sum ----------------
__global__ __launch_bounds__(256)
void k_ysum2f(const float* __restrict__ coeffw, const ushort_t* __restrict__ xbc,
              const float* __restrict__ conv_w, const float* __restrict__ conv_b,
              float* __restrict__ ypart2, ushort_t* __restrict__ xhlast){
  int b = blockIdx.x, ch = blockIdx.y;
  int tid = threadIdx.x;
  int c0 = tid * 8;
  int h = tid >> 3;
  int t0 = ch * 32;
  const float* cwt = coeffw + ((size_t)(b * 32 + h)) * 2048 + t0;
  const size_t rowbase = (size_t)b * 2048;

  float wv[8][4], cb[8];
  #pragma unroll
  for (int j = 0; j < 8; ++j){
    f32x4 w4 = *(const f32x4*)&conv_w[(c0 + j) * 4];
    #pragma unroll
    for (int k = 0; k < 4; ++k) wv[j][k] = w4[k];
    cb[j] = conv_b[c0 + j];
  }
  float h0[8], h1[8], h2[8];
  {
    float* hs[3] = {h0, h1, h2};
    #pragma unroll
    for (int k = 0; k < 3; ++k){
      int tt = t0 - 3 + k;
      if (tt >= 0){
        short8 v = *(const short8*)&xbc[(rowbase + tt) * 2304 + c0];
        #pragma unroll
        for (int j = 0; j < 8; ++j) hs[k][j] = bf2f((ushort_t)v[j]);
      } else {
        #pragma unroll
        for (int j = 0; j < 8; ++j) hs[k][j] = 0.f;
      }
    }
  }
  float acc[8] = {0.f, 0.f, 0.f, 0.f, 0.f, 0.f, 0.f, 0.f};
  float sil[8];
  for (int t = 0; t < 32; ++t){
    short8 v = *(const short8*)&xbc[(rowbase + t0 + t) * 2304 + c0];
    float cf = cwt[t];
    #pragma unroll
    for (int j = 0; j < 8; ++j){
      float xv = bf2f((ushort_t)v[j]);
      float a = cb[j] + h0[j] * wv[j][0] + h1[j] * wv[j][1] + h2[j] * wv[j][2] + xv * wv[j][3];
      float s = a / (1.f + __expf(-a));
      sil[j] = s;
      acc[j] += cf * s;
      h0[j] = h1[j]; h1[j] = h2[j]; h2[j] = xv;
    }
  }
  float* op = ypart2 + (((size_t)b * 64 + ch) * 2048) + c0;
  f32x4 o0, o1;
  #pragma unroll
  for (int j = 0; j < 4; ++j){ o0[j] = acc[j]; o1[j] = acc[4 + j]; }
  *(f32x4*)op = o0;
  *(f32x4*)(op + 4) = o1;
  if (ch == 63){
    ushort4v s0, s1;
    #pragma unroll
    for (int j = 0; j < 4; ++j){ s0[j] = f2bf(sil[j]); s1[j] = f2bf(sil[4 + j]); }
    *(ushort4v*)&xhlast[b * 2048 + c0] = s0;
    *(ushort4v*)&xhlast[b * 2048 + c0 + 4] = s1;
  }
}

// ---------------- reduce ypart chunks + D-term ----------------
__global__ void k_ysum_r2(const float* __restrict__ ypart2, const ushort_t* __restrict__ xhlast,
                          const float* __restrict__ Dp, float* __restrict__ yfin){
  int i = blockIdx.x * 256 + threadIdx.x;      // 16384
  int b = i >> 11, c = i & 2047;
  float v = 0.f;
  #pragma unroll 8
  for (int ch = 0; ch < 64; ++ch)
    v += ypart2[(((size_t)b * 64 + ch) << 11) + c];
  v += Dp[c >> 6] * bf2f(xhlast[b * 2048 + c]);
  yfin[i] = v;
}

// ---------------- gated RMSNorm ----------------
__global__ void k_norm(const float* __restrict__ yfin, const float* __restrict__ z_last,
                       const float* __restrict__ norm_w, float* __restrict__ yn){
  __shared__ float red[256];
  int b = blockIdx.x, tid = threadIdx.x;
  float vals[8], ss = 0.f;
  #pragma unroll
  for (int j = 0; j < 8; ++j){
    int c = tid + 256 * j;
    float z = z_last[b * 2048 + c];
    float yg = yfin[b * 2048 + c] * (z / (1.f + __expf(-z)));
    vals[j] = yg; ss += yg * yg;
  }
  red[tid] = ss; __syncthreads();
  for (int s = 128; s; s >>= 1){
    if (tid < s) red[tid] += red[tid + s];
    __syncthreads();
  }
  float scale = rsqrtf(red[0] / 2048.f + EPSV);
  #pragma unroll
  for (int j = 0; j < 8; ++j){
    int c = tid + 256 * j;
    yn[b * 2048 + c] = vals[j] * scale * norm_w[c];
  }
}

// ---------------- out projection: wave per column ----------------
__global__ __launch_bounds__(64)
void k_outproj(const float* __restrict__ yn, const float* __restrict__ wot,
               float* __restrict__ o){
  int col = blockIdx.x;
  int l = threadIdx.x;
  float acc[8] = {0.f, 0.f, 0.f, 0.f, 0.f, 0.f, 0.f, 0.f};
  const float* wp = wot + (size_t)col * 2048;
  #pragma unroll 4
  for (int i = 0; i < 32; ++i){
    int k = i * 64 + l;
    float w = wp[k];
    #pragma unroll
    for (int b = 0; b < 8; ++b)
      acc[b] += yn[b * 2048 + k] * w;
  }
  #pragma unroll
  for (int b = 0; b < 8; ++b){
    float v = acc[b];
    for (int s = 32; s; s >>= 1) v += __shfl_down(v, s, 64);
    if (l == 0) o[b * 1024 + col] = v;
  }
}

// ---------------- head: wave per output column ----------------
__global__ __launch_bounds__(64)
void k_head(const float* __restrict__ o, const float* __restrict__ wht,
            const float* __restrict__ b_head, float* __restrict__ out){
  int j = blockIdx.x;
  int l = threadIdx.x;
  float acc[8] = {0.f, 0.f, 0.f, 0.f, 0.f, 0.f, 0.f, 0.f};
  const float* wp = wht + (size_t)j * 1024;
  #pragma unroll 4
  for (int i = 0; i < 16; ++i){
    int k = i * 64 + l;
    float w = wp[k];
    #pragma unroll
    for (int b = 0; b < 8; ++b)
      acc[b] += o[b * 1024 + k] * w;
  }
  #pragma unroll
  for (int b = 0; b < 8; ++b){
    float v = acc[b];
    for (int s = 32; s; s >>= 1) v += __shfl_down(v, s, 64);
    if (l == 0) out[b * 64 + j] = v + b_head[j];
  }
}

extern "C" void kernel_launch(void* const* d_in, const int* in_sizes, int n_in,
                              void* d_out, int out_size, void* d_ws, size_t ws_size,
                              hipStream_t stream){
  (void)in_sizes; (void)n_in; (void)out_size; (void)ws_size;
  const float* x       = (const float*)d_in[0];
  const float* w_proj  = (const float*)d_in[1];
  const float* b_proj  = (const float*)d_in[2];
  const float* w_in    = (const float*)d_in[3];
  const float* conv_w  = (const float*)d_in[4];
  const float* conv_b  = (const float*)d_in[5];
  const float* A_log   = (const float*)d_in[6];
  const float* dt_bias = (const float*)d_in[7];
  const float* Dp      = (const float*)d_in[8];
  const float* norm_w  = (const float*)d_in[9];
  const float* w_out   = (const float*)d_in[10];
  const float* w_head  = (const float*)d_in[11];
  const float* b_head  = (const float*)d_in[12];
  float* out = (float*)d_out;

  char* ws = (char*)d_ws;
  size_t off = 0;
  auto alloc = [&](size_t bytes)->char*{
    char* p = ws + off; off += (bytes + 255) & ~(size_t)255; return p;
  };
  ushort_t* xb    = (ushort_t*)alloc((size_t)M_ROWS * 64 * 2);
  ushort_t* w1t   = (ushort_t*)alloc((size_t)1024 * 64 * 2);
  ushort_t* w2t   = (ushort_t*)alloc((size_t)2304 * 1024 * 2);
  ushort_t* wdt   = (ushort_t*)alloc((size_t)32 * 2048 * 2);
  float*    wzT   = (float*)alloc((size_t)2048 * 1024 * 4);
  float*    wot   = (float*)alloc((size_t)1024 * 2048 * 4);
  float*    wht   = (float*)alloc((size_t)64 * 1024 * 4);
  ushort_t* u16   = (ushort_t*)alloc((size_t)M_ROWS * 1024 * 2);
  ushort_t* xbc   = (ushort_t*)alloc((size_t)M_ROWS * 2304 * 2);
  float*    dtr   = (float*)alloc((size_t)M_ROWS * 32 * 4);
  float*    bmat  = (float*)alloc((size_t)M_ROWS * 128 * 4);
  float*    clast = (float*)alloc((size_t)8 * 128 * 4);
  float*    g     = (float*)alloc((size_t)M_ROWS * 4);
  float*    cfw   = (float*)alloc((size_t)256 * 2048 * 4);
  float*    ypart = (float*)alloc((size_t)8 * 64 * 2048 * 4);
  ushort_t* xhl   = (ushort_t*)alloc((size_t)8 * 2048 * 2);
  float*    yfin  = (float*)alloc((size_t)8 * 2048 * 4);
  float*    zl    = (float*)alloc((size_t)8 * 2048 * 4);
  float*    yn    = (float*)alloc((size_t)8 * 2048 * 4);
  float*    ov    = (float*)alloc((size_t)8 * 1024 * 4);

  k_prep<<<6096, 256, 0, stream>>>(x, w_proj, w_in, w_out, w_head,
                                   xb, w1t, w2t, wdt, wzT, wot, wht);

  k_gemm_bf16<<<(1024 / 128) * (M_ROWS / 128), 256, 0, stream>>>(xb, w1t, b_proj, u16, 64, 1024, 1024 / 128);

  k_fused256<<<GEMM_NB + DTG_NB + ZL_NB, 512, 0, stream>>>(u16, w2t, xbc, wdt, dtr, wzT, zl, 2304, 2304 / 256);

  dim3 gcb(32, 8);
  k_convbc<<<gcb, 256, 0, stream>>>(xbc, conv_w, conv_b, bmat, clast);

  k_gdot<<<M_ROWS / 8, 256, 0, stream>>>(bmat, clast, g);

  k_coeff<<<256, 256, 0, stream>>>(dtr, dt_bias, A_log, g, cfw);

  dim3 gy(8, 64);
  k_ysum2f<<<gy, 256, 0, stream>>>(cfw, xbc, conv_w, conv_b, ypart, xhl);

  k_ysum_r2<<<M_ROWS / 256, 256, 0, stream>>>(ypart, xhl, Dp, yfin);
  k_norm<<<8, 256, 0, stream>>>(yfin, zl, norm_w, yn);
  k_outproj<<<1024, 64, 0, stream>>>(yn, wot, ov);
  k_head<<<64, 64, 0, stream>>>(ov, wht, b_head, out);
}